// Round 3
// baseline (38339.743 us; speedup 1.0000x reference)
//
#include <hip/hip_runtime.h>
#include <math.h>

#define SW_BATCH 9
#define SW_SMALL 10
#define NPART 32

// ---- workspace float-offsets ----
#define OFF_ACCG 0
#define OFF_ACCT (NPART*4096)
#define OFF_BASE (2*NPART*4096)
#define SL_MNH  (OFF_BASE + 0*4096)
#define SL_MH   (OFF_BASE + 1*4096)
#define SL_WH   (OFF_BASE + 2*4096)
#define SL_P    (OFF_BASE + 3*4096)
#define SL_Q    (OFF_BASE + 4*4096)
#define SL_GH   (OFF_BASE + 5*4096)
#define SL_GNH  (OFF_BASE + 6*4096)
#define SL_MNH2 (OFF_BASE + 7*4096)
#define SL_WCH  (OFF_BASE + 8*4096)
#define OFF_VAR (OFF_BASE + 9*4096)
#define SL_SC   (OFF_BASE + 9*4096 + 1)

// A and V stored as 32x32 grids of 2x2 blocks (float4 = a00,a01,a10,a11),
// block pitch 33 (odd) so bank slot = 4*(i+j)&31 -> uniform under our maps.
struct Smem {
  float4 A[32*33];
  float4 V[32*33];
  float w2[64];
  float red[256];
  int flag;
};

// ---------- global row-major <-> LDS block layout (blockDim.x == 256) ----------
__device__ __forceinline__ int bidx(int r, int c) {
  return 4 * ((r >> 1) * 33 + (c >> 1)) + 2 * (r & 1) + (c & 1);
}

__device__ __forceinline__ void g2s(float4* dst, const float* __restrict__ src) {
  int t = threadIdx.x;
  float* d = (float*)dst;
#pragma unroll
  for (int i = 0; i < 16; ++i) {
    int e = t + (i << 8);
    d[bidx(e >> 6, e & 63)] = src[e];
  }
  __syncthreads();
}
__device__ __forceinline__ void g2s_scaled(float4* dst, const float* __restrict__ src, float sc) {
  int t = threadIdx.x;
  float* d = (float*)dst;
#pragma unroll
  for (int i = 0; i < 16; ++i) {
    int e = t + (i << 8);
    d[bidx(e >> 6, e & 63)] = src[e] * sc;
  }
  __syncthreads();
}
__device__ __forceinline__ void s2g(float* __restrict__ dst, const float4* src) {
  int t = threadIdx.x;
  const float* s = (const float*)src;
#pragma unroll
  for (int i = 0; i < 16; ++i) {
    int e = t + (i << 8);
    dst[e] = s[bidx(e >> 6, e & 63)];
  }
  __syncthreads();
}

// ---------- in-place 64x64 block matmuls (2-buffer choreography) ----------
// All reads complete before the pre-store barrier -> in-place is race-free.
// MODE 0: S0 <- S1*S0 ; 1: S0 <- S0*S1 ; 2: S0 <- S0*S1^T ; 3: S0 <- S0*S0 ; 4: S1 <- S0*S1
template<int MODE>
__device__ void mmIP(Smem& sm) {
  int t = threadIdx.x;
  int I = t >> 3, J0 = t & 7;
  float4 acc[4];
#pragma unroll
  for (int m = 0; m < 4; ++m) acc[m] = make_float4(0.f, 0.f, 0.f, 0.f);
  for (int k = 0; k < 32; ++k) {
    float4 x = (MODE == 0) ? sm.V[I * 33 + k] : sm.A[I * 33 + k];
#pragma unroll
    for (int m = 0; m < 4; ++m) {
      int J = J0 + 8 * m;
      float4 y;
      if (MODE == 0)      y = sm.A[k * 33 + J];
      else if (MODE == 1) y = sm.V[k * 33 + J];
      else if (MODE == 2) { float4 z = sm.V[J * 33 + k]; y = make_float4(z.x, z.z, z.y, z.w); }
      else if (MODE == 3) y = sm.A[k * 33 + J];
      else                y = sm.V[k * 33 + J];
      acc[m].x += x.x * y.x + x.y * y.z;
      acc[m].y += x.x * y.y + x.y * y.w;
      acc[m].z += x.z * y.x + x.w * y.z;
      acc[m].w += x.z * y.y + x.w * y.w;
    }
  }
  __syncthreads();
#pragma unroll
  for (int m = 0; m < 4; ++m) {
    if (MODE == 4) sm.V[I * 33 + (J0 + 8 * m)] = acc[m];
    else           sm.A[I * 33 + (J0 + 8 * m)] = acc[m];
  }
  __syncthreads();
}

// S0 <- S1 * diag(w2) * S1^T   (reads only S1/w2; S0 is dead)
__device__ void reconIP(Smem& sm) {
  __syncthreads();   // w2 visibility
  int t = threadIdx.x;
  int I = t >> 3, J0 = t & 7;
  float4 acc[4];
#pragma unroll
  for (int m = 0; m < 4; ++m) acc[m] = make_float4(0.f, 0.f, 0.f, 0.f);
  for (int k = 0; k < 32; ++k) {
    float4 x = sm.V[I * 33 + k];
    float d0 = sm.w2[2 * k], d1 = sm.w2[2 * k + 1];
    float x0 = x.x * d0, x1 = x.y * d1, x2 = x.z * d0, x3 = x.w * d1;
#pragma unroll
    for (int m = 0; m < 4; ++m) {
      float4 y = sm.V[(J0 + 8 * m) * 33 + k];
      acc[m].x += x0 * y.x + x1 * y.y;
      acc[m].y += x0 * y.z + x1 * y.w;
      acc[m].z += x2 * y.x + x3 * y.y;
      acc[m].w += x2 * y.z + x3 * y.w;
    }
  }
#pragma unroll
  for (int m = 0; m < 4; ++m) sm.A[I * 33 + (J0 + 8 * m)] = acc[m];
  __syncthreads();
}

// round-robin destination of pair i's top / bottom element (round-independent)
__device__ __forceinline__ void dests(int i, int& Pt, int& st, int& Pb, int& sb) {
  Pt = (i == 0) ? 0 : ((i == 31) ? 31 : i + 1);
  st = (i == 31) ? 1 : 0;
  Pb = (i == 0) ? 1 : (i - 1);
  sb = (i == 0) ? 0 : 1;
}

// ---------- systolic parallel Jacobi eigensolver, 64x64 symmetric ----------
// A = sm.A (destroyed; eigenvalues -> sm.w2 raw), V = sm.V.
// Pairs always at physically adjacent positions (2k,2k+1); after each round
// data moves by the fixed round-robin permutation (63 rounds = identity).
__device__ void eig64(Smem& sm, int sweeps) {
  const int t = threadIdx.x;
  const int lane = t & 63;
  const int pr = t & 31;          // own pair: A row-pair, V col-pair
  const int cg = t >> 5;          // col-group base 0..7

  // init V = I, accumulate Frobenius norm
  float nrm = 0.f;
#pragma unroll
  for (int m = 0; m < 4; ++m) {
    int bc = cg + 8 * m;
    float4 a = sm.A[pr * 33 + bc];
    nrm += a.x * a.x + a.y * a.y + a.z * a.z + a.w * a.w;
    float dg = (pr == bc) ? 1.f : 0.f;
    sm.V[pr * 33 + bc] = make_float4(dg, 0.f, 0.f, dg);
  }
  if (t == 0) sm.flag = 0;
  sm.red[t] = nrm;
  __syncthreads();
  for (int o = 128; o; o >>= 1) { if (t < o) sm.red[t] += sm.red[t + o]; __syncthreads(); }
  const float tol = 1e-6f * sqrtf(sm.red[0]) + 1e-30f;

  // precompute static scatter addresses (permutation is round-independent)
  int Ptr, str, Pbr, sbr;
  dests(pr, Ptr, str, Pbr, sbr);
  int wA[4][4], wV0[4], wV1[4];
#pragma unroll
  for (int m = 0; m < 4; ++m) {
    int bc = cg + 8 * m;
    int Ptc, stc, Pbc, sbc;
    dests(bc, Ptc, stc, Pbc, sbc);
    wA[m][0] = (Ptr * 33 + Ptc) * 4 + 2 * str + stc;
    wA[m][1] = (Ptr * 33 + Pbc) * 4 + 2 * str + sbc;
    wA[m][2] = (Pbr * 33 + Ptc) * 4 + 2 * sbr + stc;
    wA[m][3] = (Pbr * 33 + Pbc) * 4 + 2 * sbr + sbc;
    int g = cg + 8 * m;
    wV0[m] = (g * 33 + Ptr) * 4 + str;
    wV1[m] = (g * 33 + Pbr) * 4 + sbr;
  }
  float* Af = (float*)sm.A;
  float* Vf = (float*)sm.V;

  for (int s = 0; s < sweeps; ++s) {
    for (int r = 0; r < 63; ++r) {
      // batch all LDS reads for this round
      float4 ab[4], vb[4];
#pragma unroll
      for (int m = 0; m < 4; ++m) ab[m] = sm.A[pr * 33 + (cg + 8 * m)];
#pragma unroll
      for (int m = 0; m < 4; ++m) vb[m] = sm.V[(cg + 8 * m) * 33 + pr];
      float4 dg = sm.A[pr * 33 + pr];
      __syncthreads();            // reads done; writes may begin

      // own pair's rotation params (computed redundantly in both wave halves)
      float c = 1.f, s_ = 0.f;
      float app = dg.x, apq = dg.y, aqq = dg.w;
      if (fabsf(apq) > tol) {
        float tau = (aqq - app) / (2.f * apq);
        float tt = 1.f / (fabsf(tau) + sqrtf(1.f + tau * tau));
        if (tau < 0.f) tt = -tt;
        c = rsqrtf(1.f + tt * tt);
        s_ = tt * c;
        sm.flag = 1;              // benign race
      }

      // A: fused G_i * A2x2 * H_j, scatter to permuted positions
#pragma unroll
      for (int m = 0; m < 4; ++m) {
        int bc = cg + 8 * m;
        float cj = __shfl(c, bc), sj = __shfl(s_, bc);
        float4 a = ab[m];
        float b00 = c * a.x - s_ * a.z, b01 = c * a.y - s_ * a.w;
        float b10 = s_ * a.x + c * a.z, b11 = s_ * a.y + c * a.w;
        Af[wA[m][0]] = cj * b00 - sj * b01;
        Af[wA[m][1]] = sj * b00 + cj * b01;
        Af[wA[m][2]] = cj * b10 - sj * b11;
        Af[wA[m][3]] = sj * b10 + cj * b11;
      }
      // V: own pair's column rotation, scatter cols to permuted positions
#pragma unroll
      for (int m = 0; m < 4; ++m) {
        float4 v = vb[m];
        Vf[wV0[m]]     = c * v.x - s_ * v.y;
        Vf[wV1[m]]     = s_ * v.x + c * v.y;
        Vf[wV0[m] + 2] = c * v.z - s_ * v.w;
        Vf[wV1[m] + 2] = s_ * v.z + c * v.w;
      }
      __syncthreads();            // writes done before next round's reads
    }
    int f = sm.flag;
    __syncthreads();
    if (f == 0) break;            // layout is identity at sweep boundaries
    if (t == 0) sm.flag = 0;
    __syncthreads();
  }
  // eigenvalues from diagonal blocks (identity layout at exit)
  if (t < 32) {
    float4 d = sm.A[t * 33 + t];
    sm.w2[2 * t] = d.x;
    sm.w2[2 * t + 1] = d.w;
  }
  __syncthreads();
}

// ============================ kernels ============================

__global__ __launch_bounds__(256) void kzero(float* ws) {
  int i = blockIdx.x * 256 + threadIdx.x;
  if (i < OFF_BASE) ws[i] = 0.f;
  if (i == 0) ws[OFF_VAR] = 0.f;
}

__global__ __launch_bounds__(256, 4) void kprep(const float* __restrict__ weight,
                                                const float* __restrict__ M,
                                                float* ws) {
  __shared__ Smem sm;
  int t = threadIdx.x;
  g2s(sm.A, M);
  eig64(sm, SW_SMALL);
  if (t < 64) sm.w2[t] = rsqrtf(fmaxf(sm.w2[t], 1e-12f));
  reconIP(sm);
  s2g(ws + SL_MNH, sm.A);
  if (t < 64) { float v = sm.w2[t]; sm.w2[t] = 1.f / v; }   // back to sqrt(w)
  reconIP(sm);
  s2g(ws + SL_MH, sm.A);

  g2s(sm.A, weight);
  eig64(sm, SW_SMALL);
  if (t < 64) sm.w2[t] = sqrtf(fmaxf(sm.w2[t], 0.f));
  reconIP(sm);                     // S0 = Wh
  s2g(ws + SL_WH, sm.A);

  g2s(sm.V, ws + SL_MNH);
  mmIP<0>(sm);                     // S0 = Mnh*Wh
  mmIP<1>(sm);                     // S0 = Wc
  eig64(sm, SW_SMALL);
  if (t < 64) sm.w2[t] = sqrtf(fmaxf(sm.w2[t], 0.f));
  reconIP(sm);                     // S0 = Wc^{1/2}
  s2g(ws + SL_WCH, sm.A);
  if (t < 64) { float v = sm.w2[t]; sm.w2[t] = 1.f / fmaxf(v, 1e-12f); } // Wc^{-1/2} evals
  reconIP(sm);                     // S0 = Wc^{-1/2}
  g2s(sm.V, ws + SL_WH);
  mmIP<1>(sm);                     // S0 = P = Wcnh*Wh
  s2g(ws + SL_P, sm.A);

  g2s(sm.A, ws + SL_WCH);
  g2s(sm.V, ws + SL_MH);
  mmIP<0>(sm);                     // S0 = Q = Mh*Wch
  s2g(ws + SL_Q, sm.A);
}

// Xc_i = Mnh sqrt(X_i) Mnh -> out ; accumulate sum(Xc)
__global__ __launch_bounds__(256, 4) void k1(const float* __restrict__ X,
                                             float* __restrict__ out, float* ws) {
  __shared__ Smem sm;
  int t = threadIdx.x;
  size_t b = blockIdx.x;
  g2s(sm.A, X + b * 4096);
  eig64(sm, SW_BATCH);
  if (t < 64) sm.w2[t] = sqrtf(fmaxf(sm.w2[t], 0.f));
  g2s(sm.A, ws + SL_MNH);          // S0 dead post-eig
  mmIP<4>(sm);                     // S1 = U = Mnh*V
  reconIP(sm);                     // S0 = U sqrt(L) U^T = Xc
  float* Xc = out + b * 4096;
  float* acc = ws + OFF_ACCG + (size_t)(blockIdx.x & (NPART - 1)) * 4096;
  const float* Sf = (const float*)sm.A;
#pragma unroll
  for (int i = 0; i < 16; ++i) {
    int e = t + (i << 8);
    float v = Sf[bidx(e >> 6, e & 63)];
    Xc[e] = v;
    atomicAdd(acc + e, v);
  }
}

// G0 = mean(Xc); eig -> G0h, G0nh
__global__ __launch_bounds__(256, 4) void ksmall2(float* ws, float invB) {
  __shared__ Smem sm;
  int t = threadIdx.x;
  float* Af = (float*)sm.A;
#pragma unroll
  for (int i = 0; i < 16; ++i) {
    int e = t + (i << 8);
    float sum = 0.f;
    for (int p = 0; p < NPART; ++p) sum += ws[OFF_ACCG + p * 4096 + e];
    Af[bidx(e >> 6, e & 63)] = sum * invB;
  }
  __syncthreads();
  eig64(sm, SW_SMALL);
  if (t < 64) sm.w2[t] = sqrtf(fmaxf(sm.w2[t], 0.f));
  reconIP(sm);
  s2g(ws + SL_GH, sm.A);
  if (t < 64) { float v = sm.w2[t]; sm.w2[t] = 1.f / fmaxf(v, 1e-12f); }
  reconIP(sm);
  s2g(ws + SL_GNH, sm.A);
}

// accumulate sum_i log(G0nh Xc_i G0nh)
__global__ __launch_bounds__(256, 4) void k2(const float* __restrict__ XcBuf, float* ws) {
  __shared__ Smem sm;
  int t = threadIdx.x;
  size_t b = blockIdx.x;
  g2s(sm.A, XcBuf + b * 4096);
  g2s(sm.V, ws + SL_GNH);
  mmIP<0>(sm);
  mmIP<1>(sm);                     // S0 = Gnh*Xc*Gnh
  eig64(sm, SW_BATCH);
  if (t < 64) sm.w2[t] = logf(fmaxf(sm.w2[t], 1e-12f));
  reconIP(sm);
  float* acc = ws + OFF_ACCT + (size_t)(blockIdx.x & (NPART - 1)) * 4096;
  const float* Sf = (const float*)sm.A;
#pragma unroll
  for (int i = 0; i < 16; ++i) {
    int e = t + (i << 8);
    atomicAdd(acc + e, Sf[bidx(e >> 6, e & 63)]);
  }
}

// Tbar = mean ; mean_G = G0h exp(Tbar) G0h ; mnh = mean_G^{-1/2}
__global__ __launch_bounds__(256, 4) void ksmall3(float* ws, float invB) {
  __shared__ Smem sm;
  int t = threadIdx.x;
  float* Af = (float*)sm.A;
#pragma unroll
  for (int i = 0; i < 16; ++i) {
    int e = t + (i << 8);
    float sum = 0.f;
    for (int p = 0; p < NPART; ++p) sum += ws[OFF_ACCT + p * 4096 + e];
    Af[bidx(e >> 6, e & 63)] = sum * invB;
  }
  __syncthreads();
  eig64(sm, SW_SMALL);
  if (t < 64) sm.w2[t] = expf(sm.w2[t]);
  reconIP(sm);                     // S0 = E
  g2s(sm.V, ws + SL_GH);
  mmIP<0>(sm);                     // S0 = GH*E
  mmIP<1>(sm);                     // S0 = mean_G
  eig64(sm, SW_SMALL);
  if (t < 64) sm.w2[t] = rsqrtf(fmaxf(sm.w2[t], 1e-12f));
  reconIP(sm);
  s2g(ws + SL_MNH2, sm.A);
}

// T_i = log(mnh Xc_i mnh) (overwrites Xc in buf) ; accumulate ||T||_F^2
__global__ __launch_bounds__(256, 4) void k3(float* __restrict__ buf, float* ws) {
  __shared__ Smem sm;
  int t = threadIdx.x;
  size_t b = blockIdx.x;
  g2s(sm.A, buf + b * 4096);
  g2s(sm.V, ws + SL_MNH2);
  mmIP<0>(sm);
  mmIP<1>(sm);
  eig64(sm, SW_BATCH);
  if (t < 64) sm.w2[t] = logf(fmaxf(sm.w2[t], 1e-12f));
  reconIP(sm);                     // S0 = T
  float ssq = 0.f;
  float* Tg = buf + b * 4096;
  const float* Sf = (const float*)sm.A;
#pragma unroll
  for (int i = 0; i < 16; ++i) {
    int e = t + (i << 8);
    float v = Sf[bidx(e >> 6, e & 63)];
    Tg[e] = v;
    ssq += v * v;
  }
  sm.red[t] = ssq;
  __syncthreads();
  for (int o = 128; o; o >>= 1) { if (t < o) sm.red[t] += sm.red[t + o]; __syncthreads(); }
  if (t == 0) atomicAdd(ws + OFF_VAR, sm.red[0]);
}

__global__ void kscale(float* ws, const float* __restrict__ shift, float invB) {
  if (threadIdx.x == 0 && blockIdx.x == 0) {
    float var = ws[OFF_VAR] * invB;
    ws[SL_SC] = shift[0] / sqrtf(var + 1e-5f);
  }
}

// Y_i = (Q exp(scale * P T_i P^T) Q^T)^2  -> out (in place over T)
__global__ __launch_bounds__(256, 4) void k4(float* __restrict__ buf, float* ws) {
  __shared__ Smem sm;
  int t = threadIdx.x;
  size_t b = blockIdx.x;
  float sc = ws[SL_SC];
  g2s_scaled(sm.A, buf + b * 4096, sc);   // scale * T
  g2s(sm.V, ws + SL_P);
  mmIP<0>(sm);                     // P*T
  mmIP<2>(sm);                     // (P*T)*P^T
  eig64(sm, SW_BATCH);
  if (t < 64) sm.w2[t] = expf(sm.w2[t]);
  g2s(sm.A, ws + SL_Q);            // S0 dead post-eig
  mmIP<4>(sm);                     // S1 = U = Q*V
  reconIP(sm);                     // S0 = Z = U e^L U^T
  mmIP<3>(sm);                     // S0 = Z*Z
  s2g(buf + b * 4096, sm.A);
}

extern "C" void kernel_launch(void* const* d_in, const int* in_sizes, int n_in,
                              void* d_out, int out_size, void* d_ws, size_t ws_size,
                              hipStream_t stream) {
  const float* X      = (const float*)d_in[0];
  const float* weight = (const float*)d_in[1];
  const float* M      = (const float*)d_in[2];
  const float* shift  = (const float*)d_in[3];
  float* out = (float*)d_out;
  float* ws  = (float*)d_ws;
  int B = in_sizes[0] / 4096;      // 4096 matrices of 64x64
  float invB = 1.f / (float)B;

  hipLaunchKernelGGL(kzero,   dim3(OFF_BASE / 256), dim3(256), 0, stream, ws);
  hipLaunchKernelGGL(kprep,   dim3(1), dim3(256), 0, stream, weight, M, ws);
  hipLaunchKernelGGL(k1,      dim3(B), dim3(256), 0, stream, X, out, ws);
  hipLaunchKernelGGL(ksmall2, dim3(1), dim3(256), 0, stream, ws, invB);
  hipLaunchKernelGGL(k2,      dim3(B), dim3(256), 0, stream, out, ws);
  hipLaunchKernelGGL(ksmall3, dim3(1), dim3(256), 0, stream, ws, invB);
  hipLaunchKernelGGL(k3,      dim3(B), dim3(256), 0, stream, out, ws);
  hipLaunchKernelGGL(kscale,  dim3(1), dim3(64), 0, stream, ws, shift, invB);
  hipLaunchKernelGGL(k4,      dim3(B), dim3(256), 0, stream, out, ws);
}

// Round 4
// 18254.938 us; speedup vs baseline: 2.1002x; 2.1002x over previous
//
#include <hip/hip_runtime.h>
#include <math.h>

#define SW_BATCH 9
#define SW_SMALL 10
#define NPART 32
#define EPS_ROT 1e-6f

// ---- workspace float-offsets ----
#define OFF_ACCG 0
#define OFF_ACCT (NPART*4096)
#define OFF_BASE (2*NPART*4096)
#define SL_MNH  (OFF_BASE + 0*4096)
#define SL_MH   (OFF_BASE + 1*4096)
#define SL_WH   (OFF_BASE + 2*4096)
#define SL_P    (OFF_BASE + 3*4096)
#define SL_Q    (OFF_BASE + 4*4096)
#define SL_GH   (OFF_BASE + 5*4096)
#define SL_GNH  (OFF_BASE + 6*4096)
#define SL_MNH2 (OFF_BASE + 7*4096)
#define SL_WCH  (OFF_BASE + 8*4096)
#define OFF_VAR (OFF_BASE + 9*4096)
#define SL_SC   (OFF_BASE + 9*4096 + 1)

// Row-major pitch-65 storage. For a symmetric matrix, storage row k == column k,
// so Hestenes "column" ops are contiguous runs A[k*65 + r].
struct Smem {
  float S0[64*65];
  float S1[64*65];
  float w2[64];    // sigma^2 (= lambda^2) after hestenes
  float wc[64];    // recon coefficients f(lambda)/lambda^2
  float nrm[64];   // live column norms during hestenes
  float red[256];
  int flag;
};

// ---------- LDS <-> global (blockDim.x == 256) ----------
__device__ __forceinline__ void g2s(float* dst, const float* __restrict__ src) {
  int t = threadIdx.x;
#pragma unroll
  for (int i = 0; i < 16; ++i) {
    int e = t + (i << 8);
    dst[(e >> 6) * 65 + (e & 63)] = src[e];
  }
  __syncthreads();
}
__device__ __forceinline__ void g2s_scaled(float* dst, const float* __restrict__ src, float sc) {
  int t = threadIdx.x;
#pragma unroll
  for (int i = 0; i < 16; ++i) {
    int e = t + (i << 8);
    dst[(e >> 6) * 65 + (e & 63)] = src[e] * sc;
  }
  __syncthreads();
}
__device__ __forceinline__ void s2g(float* __restrict__ dst, const float* src) {
  int t = threadIdx.x;
#pragma unroll
  for (int i = 0; i < 16; ++i) {
    int e = t + (i << 8);
    dst[e] = src[(e >> 6) * 65 + (e & 63)];
  }
  __syncthreads();
}

// ---------- 64x64 matmuls, 4x4 output tile per thread (stride-16) ----------
// MODE 0: S0 <- S1*S0 ; 1: S0 <- S0*S1 ; 2: S0 <- S0*S1^T ; 3: S0 <- S1*S1
template<int MODE>
__device__ void mmX(Smem& sm) {
  int t = threadIdx.x;
  int R0 = t >> 4, J0 = t & 15;
  float acc[4][4] = {};
  for (int k = 0; k < 64; ++k) {
    float a[4], b[4];
#pragma unroll
    for (int i = 0; i < 4; ++i)
      a[i] = (MODE == 0 || MODE == 3) ? sm.S1[(R0 + 16 * i) * 65 + k]
                                      : sm.S0[(R0 + 16 * i) * 65 + k];
#pragma unroll
    for (int m = 0; m < 4; ++m) {
      if (MODE == 0)      b[m] = sm.S0[k * 65 + J0 + 16 * m];
      else if (MODE == 1) b[m] = sm.S1[k * 65 + J0 + 16 * m];
      else if (MODE == 2) b[m] = sm.S1[(J0 + 16 * m) * 65 + k];
      else                b[m] = sm.S1[k * 65 + J0 + 16 * m];
    }
#pragma unroll
    for (int i = 0; i < 4; ++i)
#pragma unroll
      for (int m = 0; m < 4; ++m) acc[i][m] = fmaf(a[i], b[m], acc[i][m]);
  }
  __syncthreads();   // all reads done before in-place overwrite
#pragma unroll
  for (int i = 0; i < 4; ++i)
#pragma unroll
    for (int m = 0; m < 4; ++m)
      sm.S0[(R0 + 16 * i) * 65 + J0 + 16 * m] = acc[i][m];
  __syncthreads();
}

// S1 <- sum_k wc[k] * S0row_k (x) S0row_k   (reads S0/wc, writes S1)
__device__ void reconT(Smem& sm) {
  __syncthreads();   // wc visibility; prior S1 readers done
  int t = threadIdx.x;
  int R0 = t >> 4, J0 = t & 15;
  float acc[4][4] = {};
  for (int k = 0; k < 64; ++k) {
    float w = sm.wc[k];
    float a[4], b[4];
#pragma unroll
    for (int i = 0; i < 4; ++i) a[i] = w * sm.S0[k * 65 + R0 + 16 * i];
#pragma unroll
    for (int m = 0; m < 4; ++m) b[m] = sm.S0[k * 65 + J0 + 16 * m];
#pragma unroll
    for (int i = 0; i < 4; ++i)
#pragma unroll
      for (int m = 0; m < 4; ++m) acc[i][m] = fmaf(a[i], b[m], acc[i][m]);
  }
#pragma unroll
  for (int i = 0; i < 4; ++i)
#pragma unroll
    for (int m = 0; m < 4; ++m)
      sm.S1[(R0 + 16 * i) * 65 + J0 + 16 * m] = acc[i][m];
  __syncthreads();
}

// Frobenius^2 of S0 (block reduction)
__device__ float frob2(Smem& sm) {
  int t = threadIdx.x;
  float s = 0.f;
#pragma unroll
  for (int i = 0; i < 16; ++i) {
    int e = t + (i << 8);
    float v = sm.S0[(e >> 6) * 65 + (e & 63)];
    s += v * v;
  }
  sm.red[t] = s;
  __syncthreads();
  for (int o = 128; o; o >>= 1) { if (t < o) sm.red[t] += sm.red[t + o]; __syncthreads(); }
  float f = sm.red[0];
  __syncthreads();
  return f;
}

// ---------- one-sided (Hestenes) Jacobi, 64x64 symmetric ----------
// S0 in: symmetric matrix (storage row k == column k).
// S0 out: columns = lambda_k * u_k (as storage rows). sm.w2[k] = lambda_k^2.
// No eigenvector matrix needed. One barrier per round.
__device__ void hestenes(Smem& sm, int sweeps) {
  const int t = threadIdx.x;
  const int g = t >> 3;     // pair/group id 0..31 (8 lanes per group)
  const int u = t & 7;      // row-slice within group
  float* A = sm.S0;

  // initial column norms (cols g and g+32 per group)
  {
    float sa = 0.f, sb = 0.f;
#pragma unroll
    for (int i = 0; i < 8; ++i) {
      float va = A[g * 65 + u + 8 * i];
      float vb = A[(g + 32) * 65 + u + 8 * i];
      sa = fmaf(va, va, sa); sb = fmaf(vb, vb, sb);
    }
    sa += __shfl_xor(sa, 1); sa += __shfl_xor(sa, 2); sa += __shfl_xor(sa, 4);
    sb += __shfl_xor(sb, 1); sb += __shfl_xor(sb, 2); sb += __shfl_xor(sb, 4);
    if (u == 0) { sm.nrm[g] = sa; sm.nrm[g + 32] = sb; }
    if (t == 0) sm.flag = 0;
  }
  __syncthreads();

  for (int s = 0; s < sweeps; ++s) {
    for (int r = 0; r < 63; ++r) {
      // round-robin pairing (32 disjoint pairs per round)
      int p, q;
      if (g == 0) { p = 63; q = r; }
      else {
        int a = r + g;      if (a >= 63) a -= 63;
        int b = r + 63 - g; if (b >= 63) b -= 63;
        p = a; q = b;
      }
      const int bp = p * 65 + u, bq = q * 65 + u;
      float cp[8], cq[8];
#pragma unroll
      for (int i = 0; i < 8; ++i) { cp[i] = A[bp + 8 * i]; cq[i] = A[bq + 8 * i]; }
      float d = 0.f;
#pragma unroll
      for (int i = 0; i < 8; ++i) d = fmaf(cp[i], cq[i], d);
      d += __shfl_xor(d, 1); d += __shfl_xor(d, 2); d += __shfl_xor(d, 4);
      float dpp = sm.nrm[p], dqq = sm.nrm[q];
      if (fabsf(d) > EPS_ROT * sqrtf(dpp * dqq)) {   // group-uniform branch
        float tau = (dqq - dpp) / (2.f * d);
        float tt = 1.f / (fabsf(tau) + sqrtf(1.f + tau * tau));
        if (tau < 0.f) tt = -tt;
        float c = rsqrtf(1.f + tt * tt);
        float s_ = tt * c;
#pragma unroll
        for (int i = 0; i < 8; ++i) {
          A[bp + 8 * i] = c * cp[i] - s_ * cq[i];
          A[bq + 8 * i] = s_ * cp[i] + c * cq[i];
        }
        if (u == 0) {
          float td = tt * d;
          sm.nrm[p] = dpp - td;    // exact Jacobi diagonal update
          sm.nrm[q] = dqq + td;
          sm.flag = 1;             // benign race
        }
      }
      __syncthreads();
    }
    int f = sm.flag;
    __syncthreads();
    if (f == 0) break;
    if (t == 0) sm.flag = 0;
    __syncthreads();
  }

  // exact final norms -> w2 = lambda^2
  {
    float sa = 0.f, sb = 0.f;
#pragma unroll
    for (int i = 0; i < 8; ++i) {
      float va = A[g * 65 + u + 8 * i];
      float vb = A[(g + 32) * 65 + u + 8 * i];
      sa = fmaf(va, va, sa); sb = fmaf(vb, vb, sb);
    }
    sa += __shfl_xor(sa, 1); sa += __shfl_xor(sa, 2); sa += __shfl_xor(sa, 4);
    sb += __shfl_xor(sb, 1); sb += __shfl_xor(sb, 2); sb += __shfl_xor(sb, 4);
    if (u == 0) { sm.w2[g] = sa; sm.w2[g + 32] = sb; }
  }
  __syncthreads();
}

// ============================ kernels ============================

__global__ __launch_bounds__(256) void kzero(float* ws) {
  int i = blockIdx.x * 256 + threadIdx.x;
  if (i < OFF_BASE) ws[i] = 0.f;
  if (i == 0) ws[OFF_VAR] = 0.f;
}

// Mnh/Mh/Wh/Wc-eig -> P = Wc^{-1/2} Wh, Q = Mh Wc^{1/2}
__global__ __launch_bounds__(256, 4) void kprep(const float* __restrict__ weight,
                                                const float* __restrict__ M,
                                                float* ws) {
  __shared__ Smem sm;
  int t = threadIdx.x;
  g2s(sm.S0, M);
  hestenes(sm, SW_SMALL);
  if (t < 64) sm.wc[t] = powf(fmaxf(sm.w2[t], 1e-12f), -1.25f);  // lambda^{-1/2-2}
  reconT(sm); s2g(ws + SL_MNH, sm.S1);
  if (t < 64) sm.wc[t] = powf(fmaxf(sm.w2[t], 1e-12f), -0.75f);  // lambda^{1/2-2}
  reconT(sm); s2g(ws + SL_MH, sm.S1);

  g2s(sm.S0, weight);
  hestenes(sm, SW_SMALL);
  if (t < 64) sm.wc[t] = powf(fmaxf(sm.w2[t], 1e-12f), -0.75f);
  reconT(sm); s2g(ws + SL_WH, sm.S1);        // S1 = Wh

  g2s(sm.S0, ws + SL_MNH);
  mmX<1>(sm);                                 // S0 = Mnh*Wh
  g2s(sm.S1, ws + SL_MNH);
  mmX<1>(sm);                                 // S0 = Wc
  hestenes(sm, SW_SMALL);
  if (t < 64) sm.wc[t] = powf(fmaxf(sm.w2[t], 1e-12f), -0.75f);
  reconT(sm); s2g(ws + SL_WCH, sm.S1);        // Wc^{1/2}
  if (t < 64) sm.wc[t] = powf(fmaxf(sm.w2[t], 1e-12f), -1.25f);
  reconT(sm);                                 // S1 = Wc^{-1/2}
  g2s(sm.S0, ws + SL_WH);
  mmX<0>(sm);                                 // S0 = Wcnh*Wh = P
  s2g(ws + SL_P, sm.S0);
  g2s(sm.S0, ws + SL_WCH);
  g2s(sm.S1, ws + SL_MH);
  mmX<0>(sm);                                 // S0 = Mh*Wch = Q
  s2g(ws + SL_Q, sm.S0);
}

// Xc_i = Mnh sqrt(X_i) Mnh -> out ; accumulate sum(Xc)
__global__ __launch_bounds__(256, 4) void k1(const float* __restrict__ X,
                                             float* __restrict__ out, float* ws) {
  __shared__ Smem sm;
  int t = threadIdx.x;
  size_t b = blockIdx.x;
  g2s(sm.S0, X + b * 4096);
  hestenes(sm, SW_BATCH);
  g2s(sm.S1, ws + SL_MNH);
  mmX<1>(sm);                                 // S0 rows = lam_k (Mnh u_k)^T
  if (t < 64) sm.wc[t] = powf(fmaxf(sm.w2[t], 1e-12f), -0.75f);  // sqrt: lam^{1/2-2}
  reconT(sm);                                 // S1 = Xc
  float* Xc = out + b * 4096;
  float* acc = ws + OFF_ACCG + (size_t)(blockIdx.x & (NPART - 1)) * 4096;
#pragma unroll
  for (int i = 0; i < 16; ++i) {
    int e = t + (i << 8);
    float v = sm.S1[(e >> 6) * 65 + (e & 63)];
    Xc[e] = v;
    atomicAdd(acc + e, v);
  }
}

// G0 = mean(Xc); eig -> G0h, G0nh
__global__ __launch_bounds__(256, 4) void ksmall2(float* ws, float invB) {
  __shared__ Smem sm;
  int t = threadIdx.x;
#pragma unroll
  for (int i = 0; i < 16; ++i) {
    int e = t + (i << 8);
    float sum = 0.f;
    for (int p = 0; p < NPART; ++p) sum += ws[OFF_ACCG + p * 4096 + e];
    sm.S0[(e >> 6) * 65 + (e & 63)] = sum * invB;
  }
  __syncthreads();
  hestenes(sm, SW_SMALL);
  if (t < 64) sm.wc[t] = powf(fmaxf(sm.w2[t], 1e-12f), -0.75f);
  reconT(sm); s2g(ws + SL_GH, sm.S1);
  if (t < 64) sm.wc[t] = powf(fmaxf(sm.w2[t], 1e-12f), -1.25f);
  reconT(sm); s2g(ws + SL_GNH, sm.S1);
}

// accumulate sum_i log(G0nh Xc_i G0nh)
__global__ __launch_bounds__(256, 4) void k2(const float* __restrict__ XcBuf, float* ws) {
  __shared__ Smem sm;
  int t = threadIdx.x;
  size_t b = blockIdx.x;
  g2s(sm.S0, XcBuf + b * 4096);
  g2s(sm.S1, ws + SL_GNH);
  mmX<1>(sm);                                 // Xc*Gnh
  mmX<0>(sm);                                 // Gnh*Xc*Gnh
  hestenes(sm, SW_BATCH);
  if (t < 64) {
    float s2 = fmaxf(sm.w2[t], 1e-12f);
    sm.wc[t] = 0.5f * logf(s2) / s2;          // log(lam)/lam^2
  }
  reconT(sm);                                 // S1 = log(.)
  float* acc = ws + OFF_ACCT + (size_t)(blockIdx.x & (NPART - 1)) * 4096;
#pragma unroll
  for (int i = 0; i < 16; ++i) {
    int e = t + (i << 8);
    atomicAdd(acc + e, sm.S1[(e >> 6) * 65 + (e & 63)]);
  }
}

// Tbar = mean ; mean_G = G0h exp(Tbar) G0h ; mnh = mean_G^{-1/2}
__global__ __launch_bounds__(256, 4) void ksmall3(float* ws, float invB) {
  __shared__ Smem sm;
  int t = threadIdx.x;
#pragma unroll
  for (int i = 0; i < 16; ++i) {
    int e = t + (i << 8);
    float sum = 0.f;
    for (int p = 0; p < NPART; ++p) sum += ws[OFF_ACCT + p * 4096 + e];
    sm.S0[(e >> 6) * 65 + (e & 63)] = sum * invB;
  }
  __syncthreads();
  // exp of symmetric INDEFINITE Tbar: shift to SPD first
  float mu = sqrtf(frob2(sm)) + 1e-3f;
  if (t < 64) sm.S0[t * 65 + t] += mu;
  __syncthreads();
  hestenes(sm, SW_SMALL);
  if (t < 64) {
    float s2 = fmaxf(sm.w2[t], 1e-12f);
    sm.wc[t] = expf(sqrtf(s2) - mu) / s2;
  }
  reconT(sm);                                 // S1 = E = exp(Tbar)
  g2s(sm.S0, ws + SL_GH);
  mmX<1>(sm);                                 // Gh*E
  g2s(sm.S1, ws + SL_GH);
  mmX<1>(sm);                                 // mean_G
  hestenes(sm, SW_SMALL);
  if (t < 64) sm.wc[t] = powf(fmaxf(sm.w2[t], 1e-12f), -1.25f);
  reconT(sm); s2g(ws + SL_MNH2, sm.S1);
}

// T_i = log(mnh Xc_i mnh) (overwrites Xc in buf) ; accumulate ||T||_F^2
__global__ __launch_bounds__(256, 4) void k3(float* __restrict__ buf, float* ws) {
  __shared__ Smem sm;
  int t = threadIdx.x;
  size_t b = blockIdx.x;
  g2s(sm.S0, buf + b * 4096);
  g2s(sm.S1, ws + SL_MNH2);
  mmX<1>(sm);
  mmX<0>(sm);
  hestenes(sm, SW_BATCH);
  if (t < 64) {
    float s2 = fmaxf(sm.w2[t], 1e-12f);
    sm.wc[t] = 0.5f * logf(s2) / s2;
  }
  reconT(sm);                                 // S1 = T
  float ssq = 0.f;
  float* Tg = buf + b * 4096;
#pragma unroll
  for (int i = 0; i < 16; ++i) {
    int e = t + (i << 8);
    float v = sm.S1[(e >> 6) * 65 + (e & 63)];
    Tg[e] = v;
    ssq += v * v;
  }
  sm.red[t] = ssq;
  __syncthreads();
  for (int o = 128; o; o >>= 1) { if (t < o) sm.red[t] += sm.red[t + o]; __syncthreads(); }
  if (t == 0) atomicAdd(ws + OFF_VAR, sm.red[0]);
}

__global__ void kscale(float* ws, const float* __restrict__ shift, float invB) {
  if (threadIdx.x == 0 && blockIdx.x == 0) {
    float var = ws[OFF_VAR] * invB;
    ws[SL_SC] = shift[0] / sqrtf(var + 1e-5f);
  }
}

// Y_i = (Q exp(scale * P T_i P^T) Q^T)^2 -> buf
__global__ __launch_bounds__(256, 4) void k4(float* __restrict__ buf, float* ws) {
  __shared__ Smem sm;
  int t = threadIdx.x;
  size_t b = blockIdx.x;
  float sc = ws[SL_SC];
  g2s_scaled(sm.S0, buf + b * 4096, sc);      // scale*T
  g2s(sm.S1, ws + SL_P);
  mmX<0>(sm);                                 // P*(scT)
  mmX<2>(sm);                                 // P*(scT)*P^T  (symmetric indefinite)
  float mu = sqrtf(frob2(sm)) + 1e-3f;
  if (t < 64) sm.S0[t * 65 + t] += mu;
  __syncthreads();
  hestenes(sm, SW_BATCH);
  if (t < 64) {
    float s2 = fmaxf(sm.w2[t], 1e-12f);
    sm.wc[t] = expf(sqrtf(s2) - mu) / s2;
  }
  g2s(sm.S1, ws + SL_Q);
  mmX<2>(sm);                                 // rows = lam (Q u)^T
  reconT(sm);                                 // S1 = Z = Q E Q^T
  mmX<3>(sm);                                 // S0 = Z*Z
  s2g(buf + b * 4096, sm.S0);
}

extern "C" void kernel_launch(void* const* d_in, const int* in_sizes, int n_in,
                              void* d_out, int out_size, void* d_ws, size_t ws_size,
                              hipStream_t stream) {
  const float* X      = (const float*)d_in[0];
  const float* weight = (const float*)d_in[1];
  const float* M      = (const float*)d_in[2];
  const float* shift  = (const float*)d_in[3];
  float* out = (float*)d_out;
  float* ws  = (float*)d_ws;
  int B = in_sizes[0] / 4096;      // 4096 matrices of 64x64
  float invB = 1.f / (float)B;

  hipLaunchKernelGGL(kzero,   dim3(OFF_BASE / 256), dim3(256), 0, stream, ws);
  hipLaunchKernelGGL(kprep,   dim3(1), dim3(256), 0, stream, weight, M, ws);
  hipLaunchKernelGGL(k1,      dim3(B), dim3(256), 0, stream, X, out, ws);
  hipLaunchKernelGGL(ksmall2, dim3(1), dim3(256), 0, stream, ws, invB);
  hipLaunchKernelGGL(k2,      dim3(B), dim3(256), 0, stream, out, ws);
  hipLaunchKernelGGL(ksmall3, dim3(1), dim3(256), 0, stream, ws, invB);
  hipLaunchKernelGGL(k3,      dim3(B), dim3(256), 0, stream, out, ws);
  hipLaunchKernelGGL(kscale,  dim3(1), dim3(64), 0, stream, ws, shift, invB);
  hipLaunchKernelGGL(k4,      dim3(B), dim3(256), 0, stream, out, ws);
}

// Round 5
// 10799.957 us; speedup vs baseline: 3.5500x; 1.6903x over previous
//
#include <hip/hip_runtime.h>
#include <math.h>

#define PITCH 72      // bank(col p, elem u) = (8p+u) mod 32: 4 slots by p mod 4,
                      // consecutive round-robin p's -> 2 lanes/bank = free (m136)
#define SW_BATCH 9
#define SW_SMALL 10
#define NPART 32
#define EPS_ROT 1e-6f

// ---- workspace float-offsets ----
#define OFF_ACCG 0
#define OFF_ACCT (NPART*4096)
#define OFF_BASE (2*NPART*4096)
#define SL_MNH  (OFF_BASE + 0*4096)
#define SL_MH   (OFF_BASE + 1*4096)
#define SL_WH   (OFF_BASE + 2*4096)
#define SL_P    (OFF_BASE + 3*4096)
#define SL_Q    (OFF_BASE + 4*4096)
#define SL_GH   (OFF_BASE + 5*4096)
#define SL_GNH  (OFF_BASE + 6*4096)
#define SL_MNH2 (OFF_BASE + 7*4096)
#define SL_WCH  (OFF_BASE + 8*4096)
#define OFF_VAR (OFF_BASE + 9*4096)
#define SL_SC   (OFF_BASE + 9*4096 + 1)

// Row-major pitch-72 storage. For a symmetric matrix, storage row k == column k,
// so Hestenes "column" ops are contiguous runs A[k*PITCH + r].
struct Smem {
  float S0[64*PITCH];
  float S1[64*PITCH];
  float w2[64];    // sigma^2 (= lambda^2) after hestenes
  float wc[64];    // recon coefficients f(lambda)/lambda^2
  float nrm[64];   // live column norms during hestenes
  float red[256];
  int flag;
};

// ---------- LDS <-> global (blockDim.x == 256) ----------
__device__ __forceinline__ void g2s(float* dst, const float* __restrict__ src) {
  int t = threadIdx.x;
#pragma unroll
  for (int i = 0; i < 16; ++i) {
    int e = t + (i << 8);
    dst[(e >> 6) * PITCH + (e & 63)] = src[e];
  }
  __syncthreads();
}
__device__ __forceinline__ void g2s_scaled(float* dst, const float* __restrict__ src, float sc) {
  int t = threadIdx.x;
#pragma unroll
  for (int i = 0; i < 16; ++i) {
    int e = t + (i << 8);
    dst[(e >> 6) * PITCH + (e & 63)] = src[e] * sc;
  }
  __syncthreads();
}
__device__ __forceinline__ void s2g(float* __restrict__ dst, const float* src) {
  int t = threadIdx.x;
#pragma unroll
  for (int i = 0; i < 16; ++i) {
    int e = t + (i << 8);
    dst[e] = src[(e >> 6) * PITCH + (e & 63)];
  }
  __syncthreads();
}

// ---------- 64x64 matmuls, 4x4 output tile per thread (stride-16) ----------
// MODE 0: S0 <- S1*S0 ; 1: S0 <- S0*S1 ; 2: S0 <- S0*S1^T ; 3: S0 <- S1*S1
template<int MODE>
__device__ void mmX(Smem& sm) {
  int t = threadIdx.x;
  int R0 = t >> 4, J0 = t & 15;
  float acc[4][4] = {};
  for (int k = 0; k < 64; ++k) {
    float a[4], b[4];
#pragma unroll
    for (int i = 0; i < 4; ++i)
      a[i] = (MODE == 0 || MODE == 3) ? sm.S1[(R0 + 16 * i) * PITCH + k]
                                      : sm.S0[(R0 + 16 * i) * PITCH + k];
#pragma unroll
    for (int m = 0; m < 4; ++m) {
      if (MODE == 0)      b[m] = sm.S0[k * PITCH + J0 + 16 * m];
      else if (MODE == 1) b[m] = sm.S1[k * PITCH + J0 + 16 * m];
      else if (MODE == 2) b[m] = sm.S1[(J0 + 16 * m) * PITCH + k];
      else                b[m] = sm.S1[k * PITCH + J0 + 16 * m];
    }
#pragma unroll
    for (int i = 0; i < 4; ++i)
#pragma unroll
      for (int m = 0; m < 4; ++m) acc[i][m] = fmaf(a[i], b[m], acc[i][m]);
  }
  __syncthreads();   // all reads done before in-place overwrite
#pragma unroll
  for (int i = 0; i < 4; ++i)
#pragma unroll
    for (int m = 0; m < 4; ++m)
      sm.S0[(R0 + 16 * i) * PITCH + J0 + 16 * m] = acc[i][m];
  __syncthreads();
}

// S1 <- sum_k wc[k] * S0row_k (x) S0row_k   (reads S0/wc, writes S1)
__device__ void reconT(Smem& sm) {
  __syncthreads();   // wc visibility; prior S1 readers done
  int t = threadIdx.x;
  int R0 = t >> 4, J0 = t & 15;
  float acc[4][4] = {};
  for (int k = 0; k < 64; ++k) {
    float w = sm.wc[k];
    float a[4], b[4];
#pragma unroll
    for (int i = 0; i < 4; ++i) a[i] = w * sm.S0[k * PITCH + R0 + 16 * i];
#pragma unroll
    for (int m = 0; m < 4; ++m) b[m] = sm.S0[k * PITCH + J0 + 16 * m];
#pragma unroll
    for (int i = 0; i < 4; ++i)
#pragma unroll
      for (int m = 0; m < 4; ++m) acc[i][m] = fmaf(a[i], b[m], acc[i][m]);
  }
#pragma unroll
  for (int i = 0; i < 4; ++i)
#pragma unroll
    for (int m = 0; m < 4; ++m)
      sm.S1[(R0 + 16 * i) * PITCH + J0 + 16 * m] = acc[i][m];
  __syncthreads();
}

// Frobenius^2 of S0 (block reduction)
__device__ float frob2(Smem& sm) {
  int t = threadIdx.x;
  float s = 0.f;
#pragma unroll
  for (int i = 0; i < 16; ++i) {
    int e = t + (i << 8);
    float v = sm.S0[(e >> 6) * PITCH + (e & 63)];
    s += v * v;
  }
  sm.red[t] = s;
  __syncthreads();
  for (int o = 128; o; o >>= 1) { if (t < o) sm.red[t] += sm.red[t + o]; __syncthreads(); }
  float f = sm.red[0];
  __syncthreads();
  return f;
}

// ---------- one-sided (Hestenes) Jacobi, 64x64 symmetric ----------
// S0 in: symmetric matrix (storage row k == column k).
// S0 out: columns = lambda_k * u_k (as storage rows). sm.w2[k] = lambda_k^2.
// No eigenvector matrix needed. One barrier per round.
__device__ void hestenes(Smem& sm, int sweeps) {
  const int t = threadIdx.x;
  const int g = t >> 3;     // pair/group id 0..31 (8 lanes per group)
  const int u = t & 7;      // row-slice within group
  float* A = sm.S0;

  // initial column norms (cols g and g+32 per group)
  {
    float sa = 0.f, sb = 0.f;
#pragma unroll
    for (int i = 0; i < 8; ++i) {
      float va = A[g * PITCH + u + 8 * i];
      float vb = A[(g + 32) * PITCH + u + 8 * i];
      sa = fmaf(va, va, sa); sb = fmaf(vb, vb, sb);
    }
    sa += __shfl_xor(sa, 1); sa += __shfl_xor(sa, 2); sa += __shfl_xor(sa, 4);
    sb += __shfl_xor(sb, 1); sb += __shfl_xor(sb, 2); sb += __shfl_xor(sb, 4);
    if (u == 0) { sm.nrm[g] = sa; sm.nrm[g + 32] = sb; }
    if (t == 0) sm.flag = 0;
  }
  __syncthreads();

  for (int s = 0; s < sweeps; ++s) {
    for (int r = 0; r < 63; ++r) {
      // round-robin pairing (32 disjoint pairs per round)
      int p, q;
      if (g == 0) { p = 63; q = r; }
      else {
        int a = r + g;      if (a >= 63) a -= 63;
        int b = r + 63 - g; if (b >= 63) b -= 63;
        p = a; q = b;
      }
      const int bp = p * PITCH + u, bq = q * PITCH + u;
      float cp[8], cq[8];
#pragma unroll
      for (int i = 0; i < 8; ++i) { cp[i] = A[bp + 8 * i]; cq[i] = A[bq + 8 * i]; }
      float d = 0.f;
#pragma unroll
      for (int i = 0; i < 8; ++i) d = fmaf(cp[i], cq[i], d);
      d += __shfl_xor(d, 1); d += __shfl_xor(d, 2); d += __shfl_xor(d, 4);
      float dpp = sm.nrm[p], dqq = sm.nrm[q];
      if (fabsf(d) > EPS_ROT * sqrtf(dpp * dqq)) {   // group-uniform branch
        float tau = (dqq - dpp) / (2.f * d);
        float tt = 1.f / (fabsf(tau) + sqrtf(1.f + tau * tau));
        if (tau < 0.f) tt = -tt;
        float c = rsqrtf(1.f + tt * tt);
        float s_ = tt * c;
#pragma unroll
        for (int i = 0; i < 8; ++i) {
          A[bp + 8 * i] = c * cp[i] - s_ * cq[i];
          A[bq + 8 * i] = s_ * cp[i] + c * cq[i];
        }
        if (u == 0) {
          float td = tt * d;
          sm.nrm[p] = dpp - td;    // exact Jacobi diagonal update
          sm.nrm[q] = dqq + td;
          sm.flag = 1;             // benign race
        }
      }
      __syncthreads();
    }
    int f = sm.flag;
    __syncthreads();
    if (f == 0) break;
    if (t == 0) sm.flag = 0;
    __syncthreads();
  }

  // exact final norms -> w2 = lambda^2
  {
    float sa = 0.f, sb = 0.f;
#pragma unroll
    for (int i = 0; i < 8; ++i) {
      float va = A[g * PITCH + u + 8 * i];
      float vb = A[(g + 32) * PITCH + u + 8 * i];
      sa = fmaf(va, va, sa); sb = fmaf(vb, vb, sb);
    }
    sa += __shfl_xor(sa, 1); sa += __shfl_xor(sa, 2); sa += __shfl_xor(sa, 4);
    sb += __shfl_xor(sb, 1); sb += __shfl_xor(sb, 2); sb += __shfl_xor(sb, 4);
    if (u == 0) { sm.w2[g] = sa; sm.w2[g + 32] = sb; }
  }
  __syncthreads();
}

// ============================ kernels ============================

__global__ __launch_bounds__(256) void kzero(float* ws) {
  int i = blockIdx.x * 256 + threadIdx.x;
  if (i < OFF_BASE) ws[i] = 0.f;
  if (i == 0) ws[OFF_VAR] = 0.f;
}

// Mnh/Mh/Wh/Wc-eig -> P = Wc^{-1/2} Wh, Q = Mh Wc^{1/2}
__global__ __launch_bounds__(256, 4) void kprep(const float* __restrict__ weight,
                                                const float* __restrict__ M,
                                                float* ws) {
  __shared__ Smem sm;
  int t = threadIdx.x;
  g2s(sm.S0, M);
  hestenes(sm, SW_SMALL);
  if (t < 64) sm.wc[t] = powf(fmaxf(sm.w2[t], 1e-12f), -1.25f);  // lambda^{-1/2-2}
  reconT(sm); s2g(ws + SL_MNH, sm.S1);
  if (t < 64) sm.wc[t] = powf(fmaxf(sm.w2[t], 1e-12f), -0.75f);  // lambda^{1/2-2}
  reconT(sm); s2g(ws + SL_MH, sm.S1);

  g2s(sm.S0, weight);
  hestenes(sm, SW_SMALL);
  if (t < 64) sm.wc[t] = powf(fmaxf(sm.w2[t], 1e-12f), -0.75f);
  reconT(sm); s2g(ws + SL_WH, sm.S1);        // S1 = Wh

  g2s(sm.S0, ws + SL_MNH);
  mmX<1>(sm);                                 // S0 = Mnh*Wh
  g2s(sm.S1, ws + SL_MNH);
  mmX<1>(sm);                                 // S0 = Wc
  hestenes(sm, SW_SMALL);
  if (t < 64) sm.wc[t] = powf(fmaxf(sm.w2[t], 1e-12f), -0.75f);
  reconT(sm); s2g(ws + SL_WCH, sm.S1);        // Wc^{1/2}
  if (t < 64) sm.wc[t] = powf(fmaxf(sm.w2[t], 1e-12f), -1.25f);
  reconT(sm);                                 // S1 = Wc^{-1/2}
  g2s(sm.S0, ws + SL_WH);
  mmX<0>(sm);                                 // S0 = Wcnh*Wh = P
  s2g(ws + SL_P, sm.S0);
  g2s(sm.S0, ws + SL_WCH);
  g2s(sm.S1, ws + SL_MH);
  mmX<0>(sm);                                 // S0 = Mh*Wch = Q
  s2g(ws + SL_Q, sm.S0);
}

// Xc_i = Mnh sqrt(X_i) Mnh -> out ; accumulate sum(Xc)
__global__ __launch_bounds__(256, 4) void k1(const float* __restrict__ X,
                                             float* __restrict__ out, float* ws) {
  __shared__ Smem sm;
  int t = threadIdx.x;
  size_t b = blockIdx.x;
  g2s(sm.S0, X + b * 4096);
  hestenes(sm, SW_BATCH);
  g2s(sm.S1, ws + SL_MNH);
  mmX<1>(sm);                                 // S0 rows = lam_k (Mnh u_k)^T
  if (t < 64) sm.wc[t] = powf(fmaxf(sm.w2[t], 1e-12f), -0.75f);  // sqrt: lam^{1/2-2}
  reconT(sm);                                 // S1 = Xc
  float* Xc = out + b * 4096;
  float* acc = ws + OFF_ACCG + (size_t)(blockIdx.x & (NPART - 1)) * 4096;
#pragma unroll
  for (int i = 0; i < 16; ++i) {
    int e = t + (i << 8);
    float v = sm.S1[(e >> 6) * PITCH + (e & 63)];
    Xc[e] = v;
    atomicAdd(acc + e, v);
  }
}

// G0 = mean(Xc); eig -> G0h, G0nh
__global__ __launch_bounds__(256, 4) void ksmall2(float* ws, float invB) {
  __shared__ Smem sm;
  int t = threadIdx.x;
#pragma unroll
  for (int i = 0; i < 16; ++i) {
    int e = t + (i << 8);
    float sum = 0.f;
    for (int p = 0; p < NPART; ++p) sum += ws[OFF_ACCG + p * 4096 + e];
    sm.S0[(e >> 6) * PITCH + (e & 63)] = sum * invB;
  }
  __syncthreads();
  hestenes(sm, SW_SMALL);
  if (t < 64) sm.wc[t] = powf(fmaxf(sm.w2[t], 1e-12f), -0.75f);
  reconT(sm); s2g(ws + SL_GH, sm.S1);
  if (t < 64) sm.wc[t] = powf(fmaxf(sm.w2[t], 1e-12f), -1.25f);
  reconT(sm); s2g(ws + SL_GNH, sm.S1);
}

// accumulate sum_i log(G0nh Xc_i G0nh)
__global__ __launch_bounds__(256, 4) void k2(const float* __restrict__ XcBuf, float* ws) {
  __shared__ Smem sm;
  int t = threadIdx.x;
  size_t b = blockIdx.x;
  g2s(sm.S0, XcBuf + b * 4096);
  g2s(sm.S1, ws + SL_GNH);
  mmX<1>(sm);                                 // Xc*Gnh
  mmX<0>(sm);                                 // Gnh*Xc*Gnh
  hestenes(sm, SW_BATCH);
  if (t < 64) {
    float s2 = fmaxf(sm.w2[t], 1e-12f);
    sm.wc[t] = 0.5f * logf(s2) / s2;          // log(lam)/lam^2
  }
  reconT(sm);                                 // S1 = log(.)
  float* acc = ws + OFF_ACCT + (size_t)(blockIdx.x & (NPART - 1)) * 4096;
#pragma unroll
  for (int i = 0; i < 16; ++i) {
    int e = t + (i << 8);
    atomicAdd(acc + e, sm.S1[(e >> 6) * PITCH + (e & 63)]);
  }
}

// Tbar = mean ; mean_G = G0h exp(Tbar) G0h ; mnh = mean_G^{-1/2}
__global__ __launch_bounds__(256, 4) void ksmall3(float* ws, float invB) {
  __shared__ Smem sm;
  int t = threadIdx.x;
#pragma unroll
  for (int i = 0; i < 16; ++i) {
    int e = t + (i << 8);
    float sum = 0.f;
    for (int p = 0; p < NPART; ++p) sum += ws[OFF_ACCT + p * 4096 + e];
    sm.S0[(e >> 6) * PITCH + (e & 63)] = sum * invB;
  }
  __syncthreads();
  // exp of symmetric INDEFINITE Tbar: shift to SPD first
  float mu = sqrtf(frob2(sm)) + 1e-3f;
  if (t < 64) sm.S0[t * PITCH + t] += mu;
  __syncthreads();
  hestenes(sm, SW_SMALL);
  if (t < 64) {
    float s2 = fmaxf(sm.w2[t], 1e-12f);
    sm.wc[t] = expf(sqrtf(s2) - mu) / s2;
  }
  reconT(sm);                                 // S1 = E = exp(Tbar)
  g2s(sm.S0, ws + SL_GH);
  mmX<1>(sm);                                 // Gh*E
  g2s(sm.S1, ws + SL_GH);
  mmX<1>(sm);                                 // mean_G
  hestenes(sm, SW_SMALL);
  if (t < 64) sm.wc[t] = powf(fmaxf(sm.w2[t], 1e-12f), -1.25f);
  reconT(sm); s2g(ws + SL_MNH2, sm.S1);
}

// T_i = log(mnh Xc_i mnh) (overwrites Xc in buf) ; accumulate ||T||_F^2
__global__ __launch_bounds__(256, 4) void k3(float* __restrict__ buf, float* ws) {
  __shared__ Smem sm;
  int t = threadIdx.x;
  size_t b = blockIdx.x;
  g2s(sm.S0, buf + b * 4096);
  g2s(sm.S1, ws + SL_MNH2);
  mmX<1>(sm);
  mmX<0>(sm);
  hestenes(sm, SW_BATCH);
  if (t < 64) {
    float s2 = fmaxf(sm.w2[t], 1e-12f);
    sm.wc[t] = 0.5f * logf(s2) / s2;
  }
  reconT(sm);                                 // S1 = T
  float ssq = 0.f;
  float* Tg = buf + b * 4096;
#pragma unroll
  for (int i = 0; i < 16; ++i) {
    int e = t + (i << 8);
    float v = sm.S1[(e >> 6) * PITCH + (e & 63)];
    Tg[e] = v;
    ssq += v * v;
  }
  sm.red[t] = ssq;
  __syncthreads();
  for (int o = 128; o; o >>= 1) { if (t < o) sm.red[t] += sm.red[t + o]; __syncthreads(); }
  if (t == 0) atomicAdd(ws + OFF_VAR, sm.red[0]);
}

__global__ void kscale(float* ws, const float* __restrict__ shift, float invB) {
  if (threadIdx.x == 0 && blockIdx.x == 0) {
    float var = ws[OFF_VAR] * invB;
    ws[SL_SC] = shift[0] / sqrtf(var + 1e-5f);
  }
}

// Y_i = (Q exp(scale * P T_i P^T) Q^T)^2 -> buf
__global__ __launch_bounds__(256, 4) void k4(float* __restrict__ buf, float* ws) {
  __shared__ Smem sm;
  int t = threadIdx.x;
  size_t b = blockIdx.x;
  float sc = ws[SL_SC];
  g2s_scaled(sm.S0, buf + b * 4096, sc);      // scale*T
  g2s(sm.S1, ws + SL_P);
  mmX<0>(sm);                                 // P*(scT)
  mmX<2>(sm);                                 // P*(scT)*P^T  (symmetric indefinite)
  float mu = sqrtf(frob2(sm)) + 1e-3f;
  if (t < 64) sm.S0[t * PITCH + t] += mu;
  __syncthreads();
  hestenes(sm, SW_BATCH);
  if (t < 64) {
    float s2 = fmaxf(sm.w2[t], 1e-12f);
    sm.wc[t] = expf(sqrtf(s2) - mu) / s2;
  }
  g2s(sm.S1, ws + SL_Q);
  mmX<2>(sm);                                 // rows = lam (Q u)^T
  reconT(sm);                                 // S1 = Z = Q E Q^T
  mmX<3>(sm);                                 // S0 = Z*Z
  s2g(buf + b * 4096, sm.S0);
}

extern "C" void kernel_launch(void* const* d_in, const int* in_sizes, int n_in,
                              void* d_out, int out_size, void* d_ws, size_t ws_size,
                              hipStream_t stream) {
  const float* X      = (const float*)d_in[0];
  const float* weight = (const float*)d_in[1];
  const float* M      = (const float*)d_in[2];
  const float* shift  = (const float*)d_in[3];
  float* out = (float*)d_out;
  float* ws  = (float*)d_ws;
  int B = in_sizes[0] / 4096;      // 4096 matrices of 64x64
  float invB = 1.f / (float)B;

  hipLaunchKernelGGL(kzero,   dim3(OFF_BASE / 256), dim3(256), 0, stream, ws);
  hipLaunchKernelGGL(kprep,   dim3(1), dim3(256), 0, stream, weight, M, ws);
  hipLaunchKernelGGL(k1,      dim3(B), dim3(256), 0, stream, X, out, ws);
  hipLaunchKernelGGL(ksmall2, dim3(1), dim3(256), 0, stream, ws, invB);
  hipLaunchKernelGGL(k2,      dim3(B), dim3(256), 0, stream, out, ws);
  hipLaunchKernelGGL(ksmall3, dim3(1), dim3(256), 0, stream, ws, invB);
  hipLaunchKernelGGL(k3,      dim3(B), dim3(256), 0, stream, out, ws);
  hipLaunchKernelGGL(kscale,  dim3(1), dim3(64), 0, stream, ws, shift, invB);
  hipLaunchKernelGGL(k4,      dim3(B), dim3(256), 0, stream, out, ws);
}